// Round 11
// baseline (189.905 us; speedup 1.0000x reference)
//
#include <hip/hip_runtime.h>
#include <hip/hip_bf16.h>
#include <math.h>
#include <stdint.h>

#define B_ 2
#define T_ 2048
#define C_ 1024
#define H_ 16
#define D_ 64

typedef __attribute__((ext_vector_type(8))) short bf16x8;
typedef __attribute__((ext_vector_type(4))) float f32x4;

__device__ inline short f2bf(float f) {
  __hip_bfloat16 h = __float2bfloat16(f);
  return *(short*)&h;
}

// async global->LDS, 16B/lane (attention staging only).
__device__ inline void async16(const void* g, void* l) {
  __builtin_amdgcn_global_load_lds(
      (const __attribute__((address_space(1))) uint32_t*)g,
      (__attribute__((address_space(3))) uint32_t*)l, 16, 0, 0);
}

// ---------------------------------------------------------------------------
// Fragment-linear layout for GEMM operands (A [M,1024] and B^T [N,1024]):
//   addr(r,k) = (r>>6)*65536 + (k>>5)*2048 + ((r>>4)&3)*512
//             + ((k>>3)&3)*128 + (r&15)*8 + (k&7)
// A wave's mfma_16x16x32 fragment (rows 16i..16i+15, k-image kk) is the
// contiguous 1 KB at panel + kk*2048 + i*512, with lane's 16B at lane*16:
// one coalesced global_load_dwordx4, straight into MFMA operand regs.
// -> GEMM needs NO LDS and NO barriers; waves pipeline independently.
// ---------------------------------------------------------------------------

// One prep kernel: blocks [0,512) convert x; [512,1280) transpose w_qkv;
// [1280,1536) transpose w_proj. All outputs fragment-linear bf16.
__global__ __launch_bounds__(256) void prep(
    const float* __restrict__ X, const float* __restrict__ Wq,
    const float* __restrict__ Wp, short* __restrict__ Xb,
    short* __restrict__ Wqt, short* __restrict__ Wpt) {
  const int tid = threadIdx.x;
  const int blk = blockIdx.x;
  __shared__ short Ts[64][68];

  if (blk < 512) {  // x -> fragment-linear bf16; thread = (row m, k-image g)
    int m = ((blk >> 5) << 8) + tid;  // consecutive tid -> consecutive m
    int g = blk & 31;
    const float* src = X + (size_t)m * C_ + g * 32;
    int base = ((m >> 6) << 16) + (g << 11) + (((m >> 4) & 3) << 9) + ((m & 15) << 3);
    short out[32];
#pragma unroll
    for (int q = 0; q < 4; ++q) {
#pragma unroll
      for (int e = 0; e < 8; e += 4) {
        float4 v = *(const float4*)(src + q * 8 + e);
        out[q * 8 + e + 0] = f2bf(v.x);
        out[q * 8 + e + 1] = f2bf(v.y);
        out[q * 8 + e + 2] = f2bf(v.z);
        out[q * 8 + e + 3] = f2bf(v.w);
      }
      *(uint4*)(Xb + base + q * 128) = *(uint4*)(out + q * 8);
    }
    return;
  }

  const float* W;
  short* Wt;
  int N, n0, k0;
  if (blk < 1280) {
    int i = blk - 512;
    W = Wq; Wt = Wqt; N = 3 * C_;
    n0 = (i % 48) * 64; k0 = (i / 48) * 64;
  } else {
    int i = blk - 1280;
    W = Wp; Wt = Wpt; N = C_;
    n0 = (i & 15) * 64; k0 = (i >> 4) * 64;
  }
  {  // stage 64k x 64n tile
    int r = tid >> 2, c0 = (tid & 3) * 16;
    const float* src = W + (size_t)(k0 + r) * N + n0 + c0;
#pragma unroll
    for (int u = 0; u < 16; u += 4) {
      float4 v = *(const float4*)(src + u);
      Ts[r][c0 + u + 0] = f2bf(v.x);
      Ts[r][c0 + u + 1] = f2bf(v.y);
      Ts[r][c0 + u + 2] = f2bf(v.z);
      Ts[r][c0 + u + 3] = f2bf(v.w);
    }
  }
  __syncthreads();
  // write fragment-linear: lane = (l16, quad, kimg/nhi); 16 lanes -> 256B runs
  {
    const int l16w = tid & 15, quadw = (tid >> 4) & 3, hi = tid >> 6;
    const int kimg2 = hi >> 1;
    const int ka = (kimg2 << 5) + (quadw << 3);
#pragma unroll
    for (int p = 0; p < 2; ++p) {
      int nloc = l16w + ((hi & 1) << 4) + (p << 5);
      short tmp[8];
#pragma unroll
      for (int u = 0; u < 8; ++u) tmp[u] = Ts[ka + u][nloc];
      int addr = ((n0 >> 6) << 16) + (((k0 >> 5) + kimg2) << 11) +
                 (((nloc >> 4) & 3) << 9) + (quadw << 7) + (l16w << 3);
      *(uint4*)(Wt + addr) = *(uint4*)tmp;
    }
  }
}

// ---------------------------------------------------------------------------
// Barrier-free bf16 MFMA GEMM. No LDS: fragments loaded straight from the
// fragment-linear global images (A dup x2 across wn, B dup x2 across wm —
// L2-resident). Manual double-buffer: loads for kimg+2 issue between MFMA
// phases; compiler inserts fine-grained vmcnt; waves never block each other.
// QKV=true: scatter epilogue -> attention-tiled Q/K/V (Q pre-scaled 0.125):
//   Q,K: [bh][t>>6][d>>3][t&63][d&7]; V: [bh][t>>6][(t&63)>>3][d][t&7]
// ---------------------------------------------------------------------------
template <int N, int BM, int BN, bool QKV>
__global__ __launch_bounds__(256, 3) void gemm_mfma(
    const short* __restrict__ A, const short* __restrict__ Bt,
    const float* __restrict__ bias, short* __restrict__ Qp,
    short* __restrict__ Kp, short* __restrict__ Vp, float* __restrict__ Cout) {
  constexpr int MI = BM / 32;  // fragments per wave (m)
  constexpr int NJ = BN / 32;  // fragments per wave (n)
  const int tid = threadIdx.x;
  const int wave = tid >> 6, lane = tid & 63;
  const int quad = lane >> 4, l16 = lane & 15;
  const int wm = wave >> 1, wn = wave & 1;
  const int m0 = blockIdx.y * BM, n0 = blockIdx.x * BN;

  int aoff[MI], boff[NJ];
#pragma unroll
  for (int i = 0; i < MI; ++i) {
    int rl = wm * (BM / 2) + i * 16;
    aoff[i] = (((m0 + rl) >> 6) << 16) + (((rl >> 4) & 3) << 9) + lane * 8;
  }
#pragma unroll
  for (int j = 0; j < NJ; ++j) {
    int cl = wn * (BN / 2) + j * 16;
    boff[j] = (((n0 + cl) >> 6) << 16) + (((cl >> 4) & 3) << 9) + lane * 8;
  }

  f32x4 acc[MI][NJ] = {};
  bf16x8 a0[MI], b0[NJ], a1[MI], b1[NJ];

  auto lda = [&](bf16x8* d, int kk) {
#pragma unroll
    for (int i = 0; i < MI; ++i)
      d[i] = *(const bf16x8*)(A + aoff[i] + kk * 2048);
  };
  auto ldb = [&](bf16x8* d, int kk) {
#pragma unroll
    for (int j = 0; j < NJ; ++j)
      d[j] = *(const bf16x8*)(Bt + boff[j] + kk * 2048);
  };
  auto mm = [&](bf16x8* a, bf16x8* b) {
#pragma unroll
    for (int i = 0; i < MI; ++i)
#pragma unroll
      for (int j = 0; j < NJ; ++j)
        acc[i][j] = __builtin_amdgcn_mfma_f32_16x16x32_bf16(a[i], b[j],
                                                            acc[i][j], 0, 0, 0);
  };

  lda(a0, 0); ldb(b0, 0);
  lda(a1, 1); ldb(b1, 1);
#pragma unroll
  for (int kk = 0; kk < 32; kk += 2) {
    mm(a0, b0);
    if (kk + 2 < 32) { lda(a0, kk + 2); ldb(b0, kk + 2); }
    mm(a1, b1);
    if (kk + 3 < 32) { lda(a1, kk + 3); ldb(b1, kk + 3); }
  }

  float bj[NJ];
#pragma unroll
  for (int j = 0; j < NJ; ++j) bj[j] = bias[n0 + wn * (BN / 2) + j * 16 + l16];

  if (QKV) {
#pragma unroll
    for (int i = 0; i < MI; ++i) {
#pragma unroll
      for (int reg = 0; reg < 4; ++reg) {
        int m = m0 + wm * (BM / 2) + i * 16 + quad * 4 + reg;
        int b = m >> 11, t = m & (T_ - 1);
#pragma unroll
        for (int j = 0; j < NJ; ++j) {
          int n = n0 + wn * (BN / 2) + j * 16 + l16;
          float v = acc[i][j][reg] + bj[j];
          int sel = n >> 10, cc = n & (C_ - 1);
          int hh = cc >> 6, d = cc & 63;
          size_t base = (size_t)(b * H_ + hh) * 131072 + (size_t)(t >> 6) * 4096;
          if (sel == 0) {
            Qp[base + (d >> 3) * 512 + (t & 63) * 8 + (d & 7)] = f2bf(v * 0.125f);
          } else if (sel == 1) {
            Kp[base + (d >> 3) * 512 + (t & 63) * 8 + (d & 7)] = f2bf(v);
          } else {
            Vp[base + ((t & 63) >> 3) * 512 + d * 8 + (t & 7)] = f2bf(v);
          }
        }
      }
    }
  } else {
#pragma unroll
    for (int i = 0; i < MI; ++i) {
#pragma unroll
      for (int reg = 0; reg < 4; ++reg) {
        int m = m0 + wm * (BM / 2) + i * 16 + quad * 4 + reg;
#pragma unroll
        for (int j = 0; j < NJ; ++j) {
          int n = n0 + wn * (BN / 2) + j * 16 + l16;
          Cout[(size_t)m * N + n] = acc[i][j][reg] + bj[j];
        }
      }
    }
  }
}

// ---------------------------------------------------------------------------
// bf16 MFMA flash attention, S^T formulation, static softmax, one barrier per
// tile, double-buffered K/V prefetch (verified round 5). Epilogue now writes
// attb in the fragment-linear GEMM-A layout (proj input).
// ---------------------------------------------------------------------------
__global__ __launch_bounds__(256, 4) void attn_kernel(
    const short* __restrict__ Qt, const short* __restrict__ Kt,
    const short* __restrict__ Vt, short* __restrict__ attb) {
  const int tid = threadIdx.x;
  const int wave = tid >> 6, lane = tid & 63;
  const int quad = lane >> 4, l16 = lane & 15;

  const int blk = blockIdx.x;
  const int bh = (blk >> 5) & 31;
  const int k2 = blk >> 8;
  int qtt = ((blk & 31) + 8 * (k2 >> 1)) & 31;
  const int qt = (k2 & 1) ? (31 - qtt) : qtt;
  const int h = bh & 15, b = bh >> 4;
  const int q0 = qt * 64;

  const short* Qg = Qt + (size_t)bh * 131072;
  const short* Kg = Kt + (size_t)bh * 131072;
  const short* Vg = Vt + (size_t)bh * 131072;

  __shared__ short Ks[2][4096];
  __shared__ short Vs[2][4096];
  __shared__ short Ps[4096];

  const int rowl = 16 * wave + l16;

  bf16x8 bq[2];
#pragma unroll
  for (int f = 0; f < 2; ++f)
    bq[f] = *(const bf16x8*)(Qg + (size_t)(qt * 8 + 4 * f + quad) * 512 +
                             rowl * 8);

  async16(Kg + tid * 8, &Ks[0][tid * 8]);
  async16(Kg + 2048 + tid * 8, &Ks[0][2048 + tid * 8]);
  async16(Vg + tid * 8, &Vs[0][tid * 8]);
  async16(Vg + 2048 + tid * 8, &Vs[0][2048 + tid * 8]);

  f32x4 oacc[4] = {};
  float lsum = 0.f;

  for (int kt = 0; kt <= qt; ++kt) {
    const int buf = kt & 1;
    __syncthreads();
    if (kt < qt) {
      const short* kp = Kg + (size_t)(kt + 1) * 4096;
      const short* vp = Vg + (size_t)(kt + 1) * 4096;
      async16(kp + tid * 8, &Ks[buf ^ 1][tid * 8]);
      async16(kp + 2048 + tid * 8, &Ks[buf ^ 1][2048 + tid * 8]);
      async16(vp + tid * 8, &Vs[buf ^ 1][tid * 8]);
      async16(vp + 2048 + tid * 8, &Vs[buf ^ 1][2048 + tid * 8]);
    }

    f32x4 sacc[4] = {};
#pragma unroll
    for (int c = 0; c < 4; ++c) {
#pragma unroll
      for (int f = 0; f < 2; ++f) {
        bf16x8 ak = *(const bf16x8*)&Ks[buf][((4 * f + quad) * 64 + 16 * c + l16) * 8];
        sacc[c] = __builtin_amdgcn_mfma_f32_16x16x32_bf16(ak, bq[f], sacc[c], 0, 0, 0);
      }
    }

    const bool diag = (kt == qt);
#pragma unroll
    for (int c = 0; c < 4; ++c) {
      short4 pk;
#pragma unroll
      for (int reg = 0; reg < 4; ++reg) {
        int keyl = 16 * c + 4 * quad + reg;
        float p = (diag && keyl > rowl) ? 0.f : __expf(sacc[c][reg]);
        lsum += p;
        ((short*)&pk)[reg] = f2bf(p);
      }
      *(short4*)&Ps[(2 * c + (quad >> 1)) * 512 + rowl * 8 + (quad & 1) * 4] = pk;
    }

    __asm__ volatile("s_waitcnt lgkmcnt(0)" ::: "memory");

    bf16x8 ap[2];
#pragma unroll
    for (int f = 0; f < 2; ++f)
      ap[f] = *(const bf16x8*)&Ps[(4 * f + quad) * 512 + rowl * 8];
#pragma unroll
    for (int n = 0; n < 4; ++n) {
#pragma unroll
      for (int f = 0; f < 2; ++f) {
        bf16x8 bv = *(const bf16x8*)&Vs[buf][((4 * f + quad) * 64 + 16 * n + l16) * 8];
        oacc[n] = __builtin_amdgcn_mfma_f32_16x16x32_bf16(ap[f], bv, oacc[n], 0, 0, 0);
      }
    }
  }

  lsum += __shfl_xor(lsum, 16);
  lsum += __shfl_xor(lsum, 32);
  float linv[4];
#pragma unroll
  for (int reg = 0; reg < 4; ++reg)
    linv[reg] = 1.0f / __shfl(lsum, 4 * quad + reg, 64);

  // Epilogue: normalize, write bf16 att in fragment-linear GEMM-A layout
#pragma unroll
  for (int reg = 0; reg < 4; ++reg) {
    const int row = q0 + 16 * wave + 4 * quad + reg;
    const int m = b * T_ + row;
    const int mpart = ((m >> 6) << 16) + (((m >> 4) & 3) << 9) + ((m & 15) << 3);
#pragma unroll
    for (int n = 0; n < 4; ++n) {
      int c = h * 64 + 16 * n + l16;
      int addr = mpart + ((c >> 5) << 11) + (((c >> 3) & 3) << 7) + (c & 7);
      attb[addr] = f2bf(oacc[n][reg] * linv[reg]);
    }
  }
}

extern "C" void kernel_launch(void* const* d_in, const int* in_sizes, int n_in,
                              void* d_out, int out_size, void* d_ws, size_t ws_size,
                              hipStream_t stream) {
  const float* x      = (const float*)d_in[0];
  const float* w_qkv  = (const float*)d_in[1];
  const float* b_qkv  = (const float*)d_in[2];
  const float* w_proj = (const float*)d_in[3];
  const float* b_proj = (const float*)d_in[4];
  float* out = (float*)d_out;

  const size_t per = (size_t)B_ * H_ * T_ * D_;  // 4.19M
  short* Qp   = (short*)d_ws;
  short* Kp   = Qp + per;
  short* Vp   = Kp + per;
  short* attb = Vp + per;                   // [4096,1024] frag-linear
  short* xb   = attb + per;                 // [4096,1024] frag-linear
  short* wqt  = xb + per;                   // [3072,1024] frag-linear
  short* wpt  = wqt + (size_t)3 * C_ * C_;  // [1024,1024] frag-linear

  prep<<<1536, 256, 0, stream>>>(x, w_qkv, w_proj, xb, wqt, wpt);

  // qkv: BM=128, BN=128 -> 24x32 = 768 blocks, barrier-free
  gemm_mfma<3 * C_, 128, 128, true><<<dim3(24, 32), 256, 0, stream>>>(
      xb, wqt, b_qkv, Qp, Kp, Vp, nullptr);

  attn_kernel<<<dim3(1024), 256, 0, stream>>>(Qp, Kp, Vp, attb);

  // proj: BM=128, BN=64 -> 16x32 = 512 blocks, barrier-free
  gemm_mfma<C_, 128, 64, false><<<dim3(16, 32), 256, 0, stream>>>(
      attb, wpt, b_proj, nullptr, nullptr, nullptr, out);
}

// Round 12
// 181.505 us; speedup vs baseline: 1.0463x; 1.0463x over previous
//
#include <hip/hip_runtime.h>
#include <hip/hip_bf16.h>
#include <math.h>
#include <stdint.h>

#define B_ 2
#define T_ 2048
#define C_ 1024
#define H_ 16
#define D_ 64

typedef __attribute__((ext_vector_type(8))) short bf16x8;
typedef __attribute__((ext_vector_type(4))) float f32x4;

__device__ inline short f2bf(float f) {
  __hip_bfloat16 h = __float2bfloat16(f);
  return *(short*)&h;
}

// async global->LDS, 16B/lane. LDS image = wave-uniform base + lane*16.
__device__ inline void async16(const void* g, void* l) {
  __builtin_amdgcn_global_load_lds(
      (const __attribute__((address_space(1))) uint32_t*)g,
      (__attribute__((address_space(3))) uint32_t*)l, 16, 0, 0);
}

// ---------------------------------------------------------------------------
// Swizzle convention for GEMM operand images (A [M,1024] and B^T [N,1024]):
// chunk p of each 32-k group holds source chunk (p ^ ((row>>1)&3)).
// Fragment reads use chunk (quad ^ ((l16>>1)&3)) -> 2-way banks (free).
// ---------------------------------------------------------------------------

// One prep kernel: blocks [0,512) convert x -> bf16 swizzled;
// [512,1280) transpose w_qkv; [1280,1536) transpose w_proj.  (R9-verified)
__global__ __launch_bounds__(256) void prep(
    const float* __restrict__ X, const float* __restrict__ Wq,
    const float* __restrict__ Wp, short* __restrict__ Xb,
    short* __restrict__ Wqt, short* __restrict__ Wpt) {
  const int tid = threadIdx.x;
  const int blk = blockIdx.x;
  __shared__ short Ts[64][68];

  if (blk < 512) {  // convert_x: one 32-k group per thread
    int t = blk * 256 + tid;
    int m = t >> 5, g = t & 31;
    const float* src = X + (size_t)m * C_ + g * 32;
    short* dst = Xb + (size_t)m * C_ + g * 32;
    int xv = (m >> 1) & 3;
    short out[32];
#pragma unroll
    for (int ch = 0; ch < 4; ++ch) {
      int sc = ch ^ xv;
#pragma unroll
      for (int e = 0; e < 8; e += 4) {
        float4 v = *(const float4*)(src + sc * 8 + e);
        out[ch * 8 + e + 0] = f2bf(v.x);
        out[ch * 8 + e + 1] = f2bf(v.y);
        out[ch * 8 + e + 2] = f2bf(v.z);
        out[ch * 8 + e + 3] = f2bf(v.w);
      }
    }
#pragma unroll
    for (int q = 0; q < 4; ++q) *(uint4*)(dst + q * 8) = *(uint4*)(out + q * 8);
    return;
  }

  const float* W;
  short* Wt;
  int N, n0, k0;
  if (blk < 1280) {
    int i = blk - 512;
    W = Wq; Wt = Wqt; N = 3 * C_;
    n0 = (i % 48) * 64; k0 = (i / 48) * 64;
  } else {
    int i = blk - 1280;
    W = Wp; Wt = Wpt; N = C_;
    n0 = (i & 15) * 64; k0 = (i >> 4) * 64;
  }
  {
    int r = tid >> 2, c0 = (tid & 3) * 16;
    const float* src = W + (size_t)(k0 + r) * N + n0 + c0;
#pragma unroll
    for (int u = 0; u < 16; u += 4) {
      float4 v = *(const float4*)(src + u);
      Ts[r][c0 + u + 0] = f2bf(v.x);
      Ts[r][c0 + u + 1] = f2bf(v.y);
      Ts[r][c0 + u + 2] = f2bf(v.z);
      Ts[r][c0 + u + 3] = f2bf(v.w);
    }
  }
  __syncthreads();
#pragma unroll
  for (int p = 0; p < 2; ++p) {
    int n = (tid >> 3) + p * 32;
    int kc = tid & 7;
    int xv = ((n0 + n) >> 1) & 3;
    int ka = kc * 8;
    int dk = (ka & ~31) | ((((ka >> 3) & 3) ^ xv) << 3);
    short tmp[8];
#pragma unroll
    for (int u = 0; u < 8; ++u) tmp[u] = Ts[ka + u][n];
    *(uint4*)(Wt + (size_t)(n0 + n) * 1024 + k0 + dk) = *(uint4*)tmp;
  }
}

// ---------------------------------------------------------------------------
// bf16 MFMA GEMM, 128xBN tile, BK=64 staged as TWO consecutive BK=32 images
// in the conflict-free swizzled [row][32k] layout (R9 structure — measured
// best: qkv 42.2us, 0 conflicts). 32 MFMA per barrier drain at BN=128.
// QKV=true: scatter epilogue -> attention-tiled Q/K/V (Q pre-scaled 0.125):
//   Q,K: [bh][t>>6][d>>3][t&63][d&7]; V: [bh][t>>6][(t&63)>>3][d][t&7]
// ---------------------------------------------------------------------------
template <int N, int BN, bool QKV>
__global__ __launch_bounds__(256) void gemm_mfma(
    const short* __restrict__ A, const short* __restrict__ Bt,
    const float* __restrict__ bias, short* __restrict__ Qp,
    short* __restrict__ Kp, short* __restrict__ Vp, float* __restrict__ Cout) {
  constexpr int NJ = BN / 32;      // n-tiles per wave
  constexpr int BI = BN * 32;      // B image size (shorts)
  const int tid = threadIdx.x;
  const int wave = tid >> 6, lane = tid & 63;
  const int quad = lane >> 4, l16 = lane & 15;
  const int wm = wave >> 1, wn = wave & 1;
  const int m0 = blockIdx.y * 128, n0 = blockIdx.x * BN;

  __shared__ short As[2][4096];    // two 32-k images, [row][32k] swizzled
  __shared__ short Bs[2][BI];

  const int srow = tid >> 2, skc = tid & 3;
  const size_t arow0 = (size_t)(m0 + srow) * 1024 + skc * 8;
  const size_t brow0 = (size_t)(n0 + srow) * 1024 + skc * 8;

  f32x4 acc[4][NJ] = {};

  const int xi = quad ^ ((l16 >> 1) & 3);  // de-swizzle chunk select
  int aoff[4], boff[NJ];
#pragma unroll
  for (int i = 0; i < 4; ++i) aoff[i] = (wm * 64 + i * 16 + l16) * 32 + xi * 8;
#pragma unroll
  for (int j = 0; j < NJ; ++j)
    boff[j] = (wn * (BN / 2) + j * 16 + l16) * 32 + xi * 8;

  for (int k0 = 0; k0 < 1024; k0 += 64) {
    __syncthreads();  // prior reads done before overwrite
#pragma unroll
    for (int f = 0; f < 2; ++f) {
      const int kf = k0 + f * 32;
      async16(A + arow0 + kf, &As[f][tid * 8]);
      async16(A + arow0 + (size_t)64 * 1024 + kf, &As[f][2048 + tid * 8]);
      async16(Bt + brow0 + kf, &Bs[f][tid * 8]);
      if (BN == 128)
        async16(Bt + brow0 + (size_t)64 * 1024 + kf, &Bs[f][2048 + tid * 8]);
    }
    __syncthreads();  // staging visible (vmcnt drained by barrier)

#pragma unroll
    for (int f = 0; f < 2; ++f) {
      bf16x8 af[4], bfr[NJ];
#pragma unroll
      for (int i = 0; i < 4; ++i) af[i] = *(const bf16x8*)&As[f][aoff[i]];
#pragma unroll
      for (int j = 0; j < NJ; ++j) bfr[j] = *(const bf16x8*)&Bs[f][boff[j]];
#pragma unroll
      for (int i = 0; i < 4; ++i)
#pragma unroll
        for (int j = 0; j < NJ; ++j)
          acc[i][j] = __builtin_amdgcn_mfma_f32_16x16x32_bf16(
              af[i], bfr[j], acc[i][j], 0, 0, 0);
    }
  }

  float bj[NJ];
#pragma unroll
  for (int j = 0; j < NJ; ++j) bj[j] = bias[n0 + wn * (BN / 2) + j * 16 + l16];

  if (QKV) {
#pragma unroll
    for (int i = 0; i < 4; ++i) {
#pragma unroll
      for (int reg = 0; reg < 4; ++reg) {
        int m = m0 + wm * 64 + i * 16 + quad * 4 + reg;
        int b = m >> 11, t = m & (T_ - 1);
#pragma unroll
        for (int j = 0; j < NJ; ++j) {
          int n = n0 + wn * (BN / 2) + j * 16 + l16;
          float v = acc[i][j][reg] + bj[j];
          int sel = n >> 10, cc = n & (C_ - 1);
          int hh = cc >> 6, d = cc & 63;
          size_t base = (size_t)(b * H_ + hh) * 131072 + (size_t)(t >> 6) * 4096;
          if (sel == 0) {
            Qp[base + (d >> 3) * 512 + (t & 63) * 8 + (d & 7)] = f2bf(v * 0.125f);
          } else if (sel == 1) {
            Kp[base + (d >> 3) * 512 + (t & 63) * 8 + (d & 7)] = f2bf(v);
          } else {
            Vp[base + ((t & 63) >> 3) * 512 + d * 8 + (t & 7)] = f2bf(v);
          }
        }
      }
    }
  } else {
#pragma unroll
    for (int i = 0; i < 4; ++i) {
#pragma unroll
      for (int reg = 0; reg < 4; ++reg) {
        int m = m0 + wm * 64 + i * 16 + quad * 4 + reg;
#pragma unroll
        for (int j = 0; j < NJ; ++j) {
          int n = n0 + wn * (BN / 2) + j * 16 + l16;
          Cout[(size_t)m * N + n] = acc[i][j][reg] + bj[j];
        }
      }
    }
  }
}

// ---------------------------------------------------------------------------
// bf16 MFMA flash attention, 128-QUERY blocks (2 query-64-tiles per staged
// K/V tile): 32 MFMA per barrier drain (vs 16 at 64q), half the K/V staging
// traffic. S^T formulation, static softmax, dbuf K/V prefetch (R5-verified
// core). Wave w owns strip rows 32w..32w+31 (query 64-tile tq = 2qt+(w>>1));
// per-wave uniform branch: kt<tq clean, kt==tq diag-masked, kt>tq skipped
// (barrier/prefetch still uniform across all waves).
// ---------------------------------------------------------------------------
__global__ __launch_bounds__(256, 3) void attn_kernel(
    const short* __restrict__ Qt, const short* __restrict__ Kt,
    const short* __restrict__ Vt, short* __restrict__ attb) {
  const int tid = threadIdx.x;
  const int wave = tid >> 6, lane = tid & 63;
  const int quad = lane >> 4, l16 = lane & 15;

  // 512 blocks: bh = blk&31; strips paired (s, 15-s) across grid halves
  const int blk = blockIdx.x;
  const int bh = blk & 31;
  const int s3 = (blk >> 5) & 7;
  const int qt = (blk & 256) ? (15 - s3) : s3;
  const int h = bh & 15, b = bh >> 4;
  const int q0 = qt * 128;

  const int tq = 2 * qt + (wave >> 1);  // wave's query 64-tile index
  const int KT = 2 * qt + 2;            // key tiles to stage
  const int rloc = 32 * (wave & 1) + l16;  // query pos base within 64-tile

  const short* Qg = Qt + (size_t)bh * 131072;
  const short* Kg = Kt + (size_t)bh * 131072;
  const short* Vg = Vt + (size_t)bh * 131072;

  __shared__ short Ks[2][4096];
  __shared__ short Vs[2][4096];
  __shared__ short Ps[8192];  // [key>>3][row 0..127][key&7]

  // Q B-frags (loop-invariant): rg = row-group of 16 within wave's 32 rows
  bf16x8 bq[2][2];
#pragma unroll
  for (int rg = 0; rg < 2; ++rg)
#pragma unroll
    for (int f = 0; f < 2; ++f)
      bq[rg][f] = *(const bf16x8*)(Qg + (size_t)(tq * 8 + 4 * f + quad) * 512 +
                                   (rloc + 16 * rg) * 8);

  // stage tile 0
  async16(Kg + tid * 8, &Ks[0][tid * 8]);
  async16(Kg + 2048 + tid * 8, &Ks[0][2048 + tid * 8]);
  async16(Vg + tid * 8, &Vs[0][tid * 8]);
  async16(Vg + 2048 + tid * 8, &Vs[0][2048 + tid * 8]);

  f32x4 oacc[2][4] = {};
  float lsum[2] = {0.f, 0.f};

  for (int kt = 0; kt < KT; ++kt) {
    const int buf = kt & 1;
    __syncthreads();  // drains vmcnt: Ks/Vs[buf] ready
    if (kt + 1 < KT) {  // prefetch kt+1 -> drained at next barrier
      const short* kp = Kg + (size_t)(kt + 1) * 4096;
      const short* vp = Vg + (size_t)(kt + 1) * 4096;
      async16(kp + tid * 8, &Ks[buf ^ 1][tid * 8]);
      async16(kp + 2048 + tid * 8, &Ks[buf ^ 1][2048 + tid * 8]);
      async16(vp + tid * 8, &Vs[buf ^ 1][tid * 8]);
      async16(vp + 2048 + tid * 8, &Vs[buf ^ 1][2048 + tid * 8]);
    }

    if (kt <= tq) {  // wave-uniform: skip all-masked tile for upper waves
      // S^T = K·Q^T for both row-groups
      f32x4 sacc[2][4] = {};
#pragma unroll
      for (int c = 0; c < 4; ++c) {
#pragma unroll
        for (int f = 0; f < 2; ++f) {
          bf16x8 ak =
              *(const bf16x8*)&Ks[buf][((4 * f + quad) * 64 + 16 * c + l16) * 8];
#pragma unroll
          for (int rg = 0; rg < 2; ++rg)
            sacc[rg][c] = __builtin_amdgcn_mfma_f32_16x16x32_bf16(
                ak, bq[rg][f], sacc[rg][c], 0, 0, 0);
        }
      }

      const bool diag = (kt == tq);
#pragma unroll
      for (int rg = 0; rg < 2; ++rg) {
        const int qloc = rloc + 16 * rg;           // query pos in 64-tile
        const int rs = 32 * wave + 16 * rg + l16;  // row in strip (0..127)
#pragma unroll
        for (int c = 0; c < 4; ++c) {
          short4 pk;
#pragma unroll
          for (int reg = 0; reg < 4; ++reg) {
            int keyl = 16 * c + 4 * quad + reg;
            float p = (diag && keyl > qloc) ? 0.f : __expf(sacc[rg][c][reg]);
            lsum[rg] += p;
            ((short*)&pk)[reg] = f2bf(p);
          }
          *(short4*)&Ps[(2 * c + (quad >> 1)) * 1024 + rs * 8 + (quad & 1) * 4] =
              pk;
        }
      }

      __asm__ volatile("s_waitcnt lgkmcnt(0)" ::: "memory");  // own-row wr->rd

      // O += P·V
      bf16x8 ap[2][2];
#pragma unroll
      for (int rg = 0; rg < 2; ++rg)
#pragma unroll
        for (int f = 0; f < 2; ++f)
          ap[rg][f] = *(const bf16x8*)&Ps[(4 * f + quad) * 1024 +
                                          (32 * wave + 16 * rg + l16) * 8];
#pragma unroll
      for (int n = 0; n < 4; ++n) {
#pragma unroll
        for (int f = 0; f < 2; ++f) {
          bf16x8 bv =
              *(const bf16x8*)&Vs[buf][((4 * f + quad) * 64 + 16 * n + l16) * 8];
#pragma unroll
          for (int rg = 0; rg < 2; ++rg)
            oacc[rg][n] = __builtin_amdgcn_mfma_f32_16x16x32_bf16(
                ap[rg][f], bv, oacc[rg][n], 0, 0, 0);
        }
      }
    }
  }

  // deferred l-reduction + epilogue (bf16 att in GEMM-A swizzled layout)
#pragma unroll
  for (int rg = 0; rg < 2; ++rg) {
    float ls = lsum[rg];
    ls += __shfl_xor(ls, 16);
    ls += __shfl_xor(ls, 32);
#pragma unroll
    for (int reg = 0; reg < 4; ++reg) {
      const float linv = 1.0f / __shfl(ls, 4 * quad + reg, 64);
      const int row = q0 + 32 * wave + 16 * rg + 4 * quad + reg;
      const int m = b * T_ + row;
      const int xv = (m >> 1) & 3;
#pragma unroll
      for (int n = 0; n < 4; ++n) {
        int c = h * 64 + 16 * n + l16;
        int cs = (c & ~31) | ((((c >> 3) & 3) ^ xv) << 3) | (c & 7);
        attb[(size_t)m * C_ + cs] = f2bf(oacc[rg][n][reg] * linv);
      }
    }
  }
}

extern "C" void kernel_launch(void* const* d_in, const int* in_sizes, int n_in,
                              void* d_out, int out_size, void* d_ws, size_t ws_size,
                              hipStream_t stream) {
  const float* x      = (const float*)d_in[0];
  const float* w_qkv  = (const float*)d_in[1];
  const float* b_qkv  = (const float*)d_in[2];
  const float* w_proj = (const float*)d_in[3];
  const float* b_proj = (const float*)d_in[4];
  float* out = (float*)d_out;

  const size_t per = (size_t)B_ * H_ * T_ * D_;  // 4.19M
  short* Qp   = (short*)d_ws;
  short* Kp   = Qp + per;
  short* Vp   = Kp + per;
  short* attb = Vp + per;                   // [4096,1024] bf16 swizzled
  short* xb   = attb + per;                 // [4096,1024] bf16 swizzled
  short* wqt  = xb + per;                   // [3072,1024] bf16 swizzled
  short* wpt  = wqt + (size_t)3 * C_ * C_;  // [1024,1024] bf16 swizzled

  prep<<<1536, 256, 0, stream>>>(x, w_qkv, w_proj, xb, wqt, wpt);

  // qkv: BM=128, BN=128 -> 24x32 = 768 blocks (R9 config)
  gemm_mfma<3 * C_, 128, true><<<dim3(24, 32), 256, 0, stream>>>(
      xb, wqt, b_qkv, Qp, Kp, Vp, nullptr);

  // attn: 128-query blocks -> 512 blocks
  attn_kernel<<<dim3(512), 256, 0, stream>>>(Qp, Kp, Vp, attb);

  // proj: BM=128, BN=64 -> 16x32 = 512 blocks (R9 config)
  gemm_mfma<C_, 64, false><<<dim3(16, 32), 256, 0, stream>>>(
      attb, wpt, b_proj, nullptr, nullptr, nullptr, out);
}